// Round 5
// baseline (277.543 us; speedup 1.0000x reference)
//
#include <hip/hip_runtime.h>
#include <hip/hip_fp16.h>

// ---------------------------------------------------------------------------
// GCN pipeline v5: fp16 gather features, 4B CSR, trimmed dispatch count (13).
// N=50000 nodes, E=800000 edges, H=F=64, G=512 graphs, C=10 classes
// ---------------------------------------------------------------------------

// Single-block: detect whether mask is bytes (some word >1) or int32 0/1.
__global__ void k_detect(const unsigned int* __restrict__ m, int n_ints,
                         int* __restrict__ flag) {
  __shared__ int found;
  if (threadIdx.x == 0) found = 0;
  __syncthreads();
  int loc = 0;
  for (int i = threadIdx.x; i < n_ints; i += blockDim.x)
    if (m[i] > 1u) loc = 1;
  if (loc) found = 1;
  __syncthreads();
  if (threadIdx.x == 0) *flag = found;
}

// maskf + zero cnt + init gs/ge + convert x -> fp16 xh (grid covers N*64)
__global__ void k_prep(const float* __restrict__ x, __half* __restrict__ xh,
                       const void* __restrict__ mraw, const int* __restrict__ flag,
                       float* __restrict__ maskf, int* __restrict__ cnt,
                       int* __restrict__ gs, int* __restrict__ ge,
                       long total, int N, int G) {
  long idx = (long)blockIdx.x * blockDim.x + threadIdx.x;
  if (idx < total) xh[idx] = __float2half_rn(x[idx]);
  if (idx < G) { gs[idx] = 0x7fffffff; ge[idx] = -1; }
  if (idx < N) {
    float v;
    if (*flag) v = (float)((const unsigned char*)mraw)[idx];
    else       v = (float)((const int*)mraw)[idx];
    maskf[idx] = v;
    cnt[idx] = 0;
  }
}

// cnt[d] += 1 for each edge with both endpoints kept
__global__ void k_cnt(const int* __restrict__ src, const int* __restrict__ dst,
                      const float* __restrict__ maskf, int* __restrict__ cnt, int E) {
  int e = blockIdx.x * blockDim.x + threadIdx.x;
  if (e >= E) return;
  int s = src[e], d = dst[e];
  if (maskf[s] != 0.f && maskf[d] != 0.f) atomicAdd(&cnt[d], 1);
}

// block-local exclusive scan of cnt + dinv
__global__ void k_scan1(const int* __restrict__ cnt, const float* __restrict__ maskf,
                        float* __restrict__ dinv, int* __restrict__ off,
                        int* __restrict__ bsum, int N) {
  __shared__ int s[256];
  int i = blockIdx.x * 256 + threadIdx.x;
  int v = (i < N) ? cnt[i] : 0;
  if (i < N) {
    float d = (float)v + maskf[i];
    dinv[i] = (d > 0.f) ? rsqrtf(d) : 0.f;
  }
  s[threadIdx.x] = v;
  __syncthreads();
#pragma unroll
  for (int d = 1; d < 256; d <<= 1) {
    int t = (threadIdx.x >= d) ? s[threadIdx.x - d] : 0;
    __syncthreads();
    s[threadIdx.x] += t;
    __syncthreads();
  }
  if (i < N) off[i] = s[threadIdx.x] - v;
  if (threadIdx.x == 255) bsum[blockIdx.x] = s[255];
}

// finalize offsets (each block re-scans bsum in LDS; nb <= 256) + cursor +
// per-graph bounds via sorted-batch boundary detection (no atomics)
__global__ void k_scan3(int* __restrict__ off, const int* __restrict__ bsum, int nb,
                        int* __restrict__ cursor, const int* __restrict__ batch,
                        int* __restrict__ gs, int* __restrict__ ge, int N) {
  __shared__ int s[256];
  __shared__ int prefix;
  int v = (threadIdx.x < nb) ? bsum[threadIdx.x] : 0;
  s[threadIdx.x] = v;
  __syncthreads();
#pragma unroll
  for (int d = 1; d < 256; d <<= 1) {
    int t = (threadIdx.x >= d) ? s[threadIdx.x - d] : 0;
    __syncthreads();
    s[threadIdx.x] += t;
    __syncthreads();
  }
  if (threadIdx.x == blockIdx.x) prefix = s[threadIdx.x] - v;  // exclusive
  __syncthreads();
  int i = blockIdx.x * 256 + threadIdx.x;
  if (i >= N) return;
  int o = off[i] + prefix;
  off[i] = o;
  cursor[i] = o;
  int b = batch[i];
  if (i == 0 || batch[i - 1] != b) gs[b] = i;
  if (i == N - 1 || batch[i + 1] != b) ge[b] = i;
}

// Fill CSR: src index per kept edge, grouped by dst (4 B/entry).
__global__ void k_fill(const int* __restrict__ src, const int* __restrict__ dst,
                       const float* __restrict__ dinv, int* __restrict__ cursor,
                       int* __restrict__ csr, int E) {
  int e = blockIdx.x * blockDim.x + threadIdx.x;
  if (e >= E) return;
  int s = src[e], d = dst[e];
  if (dinv[s] != 0.f && dinv[d] != 0.f) {
    int p = atomicAdd(&cursor[d], 1);
    csr[p] = s;
  }
}

// P[d][:] = dinv[d]^2 * Hh[d][:] + sum_e w_e * Hh[src_e][:]  (Hh fp16, P f32)
// One wave per dst; 8 edges/iter via 8-lane groups; each lane: 8 cols = one
// 16B load. Weights recomputed from dinv (L1-hot) at chunk preload.
__global__ __launch_bounds__(256) void k_agg(const __half* __restrict__ Hh,
                                             const float* __restrict__ dinv,
                                             const int* __restrict__ off,
                                             const int* __restrict__ cnt,
                                             const int* __restrict__ csr,
                                             float* __restrict__ P, int N) {
  const int lane = threadIdx.x & 63;
  const int wid = threadIdx.x >> 6;
  const int d = blockIdx.x * 4 + wid;
  if (d >= N) return;
  const int grp = lane >> 3;   // which edge of the octet
  const int q = lane & 7;      // column group: cols 8q..8q+7
  const int base = off[d];
  const int n = cnt[d];
  const float dinv_d = dinv[d];
  float4 a0 = make_float4(0.f, 0.f, 0.f, 0.f);
  float4 a1 = make_float4(0.f, 0.f, 0.f, 0.f);
  int done = 0;
  while (done < n) {
    const int chunk = min(n - done, 64);
    int sl = (lane < chunk) ? csr[base + done + lane] : 0;
    float wl = (lane < chunk) ? dinv[sl] * dinv_d : 0.f;
    const int rounds = (chunk + 7) & ~7;
#pragma unroll 2
    for (int i = 0; i < rounds; i += 8) {
      const int j = i + grp;
      const int s = __shfl(sl, j);
      const float w = __shfl(wl, j);  // 0 for padded lanes
      const float4 raw = *(const float4*)&Hh[(long)s * 64 + q * 8];
      const __half2* hp = (const __half2*)&raw;
      const float2 f0 = __half22float2(hp[0]);
      const float2 f1 = __half22float2(hp[1]);
      const float2 f2 = __half22float2(hp[2]);
      const float2 f3 = __half22float2(hp[3]);
      a0.x = fmaf(f0.x, w, a0.x);
      a0.y = fmaf(f0.y, w, a0.y);
      a0.z = fmaf(f1.x, w, a0.z);
      a0.w = fmaf(f1.y, w, a0.w);
      a1.x = fmaf(f2.x, w, a1.x);
      a1.y = fmaf(f2.y, w, a1.y);
      a1.z = fmaf(f3.x, w, a1.z);
      a1.w = fmaf(f3.y, w, a1.w);
    }
    done += chunk;
  }
  // reduce the 8 edge-groups (lanes sharing q share columns)
#pragma unroll
  for (int m = 8; m <= 32; m <<= 1) {
    a0.x += __shfl_xor(a0.x, m);
    a0.y += __shfl_xor(a0.y, m);
    a0.z += __shfl_xor(a0.z, m);
    a0.w += __shfl_xor(a0.w, m);
    a1.x += __shfl_xor(a1.x, m);
    a1.y += __shfl_xor(a1.y, m);
    a1.z += __shfl_xor(a1.z, m);
    a1.w += __shfl_xor(a1.w, m);
  }
  if (grp == 0) {
    const float dii = dinv_d * dinv_d;
    const float4 raw = *(const float4*)&Hh[(long)d * 64 + q * 8];
    const __half2* hp = (const __half2*)&raw;
    const float2 f0 = __half22float2(hp[0]);
    const float2 f1 = __half22float2(hp[1]);
    const float2 f2 = __half22float2(hp[2]);
    const float2 f3 = __half22float2(hp[3]);
    a0.x = fmaf(f0.x, dii, a0.x);
    a0.y = fmaf(f0.y, dii, a0.y);
    a0.z = fmaf(f1.x, dii, a0.z);
    a0.w = fmaf(f1.y, dii, a0.w);
    a1.x = fmaf(f2.x, dii, a1.x);
    a1.y = fmaf(f2.y, dii, a1.y);
    a1.z = fmaf(f3.x, dii, a1.z);
    a1.w = fmaf(f3.y, dii, a1.w);
    *(float4*)&P[(long)d * 64 + q * 8] = a0;
    *(float4*)&P[(long)d * 64 + q * 8 + 4] = a1;
  }
}

// Hout = relu(A @ W + b); one wave per row, W column per lane.
// HALFOUT: write fp16 (feeds next layer's gather) else f32 (feeds pool).
template <bool HALFOUT>
__global__ __launch_bounds__(256) void k_gemm(const float* __restrict__ A,
                                              const float* __restrict__ W,
                                              const float* __restrict__ b,
                                              void* __restrict__ T, int nrows) {
  const int lane = threadIdx.x & 63;
  const int wid = threadIdx.x >> 6;
  float wcol[64];
#pragma unroll
  for (int k = 0; k < 64; ++k) wcol[k] = W[k * 64 + lane];
  const float bl = b[lane];
  for (int r = blockIdx.x * 4 + wid; r < nrows; r += gridDim.x * 4) {
    const float av = A[(long)r * 64 + lane];
    float acc = bl;
#pragma unroll
    for (int k = 0; k < 64; ++k) acc = fmaf(__shfl(av, k), wcol[k], acc);
    acc = fmaxf(acc, 0.f);
    if (HALFOUT) ((__half*)T)[(long)r * 64 + lane] = __float2half_rn(acc);
    else         ((float*)T)[(long)r * 64 + lane] = acc;
  }
}

// Fused: per-graph max-pool over kept nodes -> MLP head -> out[grp][:]
__global__ __launch_bounds__(256) void k_pool_head(
    const float* __restrict__ H, const float* __restrict__ maskf,
    const int* __restrict__ gs, const int* __restrict__ ge,
    const float* __restrict__ fw1, const float* __restrict__ fb1,
    const float* __restrict__ fw2, const float* __restrict__ fb2,
    float* __restrict__ out, int N, int C) {
  __shared__ float sP[4][64];
  __shared__ float sg[64];
  __shared__ float sg2[64];
  const int grp = blockIdx.x;
  const int lane = threadIdx.x & 63, wid = threadIdx.x >> 6;
  const int s = gs[grp], e = ge[grp];
  float v = 0.f;
  if (s <= e) {
    for (int i = s + wid; i <= e; i += 4)
      if (maskf[i] != 0.f) v = fmaxf(v, H[(long)i * 64 + lane]);
  }
  sP[wid][lane] = v;
  __syncthreads();
  if (wid == 0)
    sg[lane] = fmaxf(fmaxf(sP[0][lane], sP[1][lane]), fmaxf(sP[2][lane], sP[3][lane]));
  __syncthreads();
  if (threadIdx.x < 64) {
    const int f = threadIdx.x;
    float acc = fb1[f];
#pragma unroll 8
    for (int k = 0; k < 64; ++k) acc = fmaf(sg[k], fw1[k * 64 + f], acc);
    sg2[f] = fmaxf(acc, 0.f);
  }
  __syncthreads();
  if (threadIdx.x < C) {
    const int c = threadIdx.x;
    float acc = fb2[c];
#pragma unroll 8
    for (int k = 0; k < 64; ++k) acc = fmaf(sg2[k], fw2[k * C + c], acc);
    out[grp * C + c] = acc;
  }
}

extern "C" void kernel_launch(void* const* d_in, const int* in_sizes, int n_in,
                              void* d_out, int out_size, void* d_ws, size_t ws_size,
                              hipStream_t stream) {
  const float* x    = (const float*)d_in[0];
  const int*   ei   = (const int*)d_in[1];
  const int*   batch= (const int*)d_in[2];
  const void*  mraw = d_in[3];
  const float* W1   = (const float*)d_in[4];
  const float* b1   = (const float*)d_in[5];
  const float* W2   = (const float*)d_in[6];
  const float* b2   = (const float*)d_in[7];
  const float* W3   = (const float*)d_in[8];
  const float* b3   = (const float*)d_in[9];
  const float* fw1  = (const float*)d_in[10];
  const float* fb1  = (const float*)d_in[11];
  const float* fw2  = (const float*)d_in[12];
  const float* fb2  = (const float*)d_in[13];
  float* out = (float*)d_out;

  const int N = in_sizes[0] / 64;
  const int E = in_sizes[1] / 2;
  const int C = in_sizes[13];
  const int* src = ei;
  const int* dst = ei + E;
  const int G = out_size / C;

  char* ws = (char*)d_ws;
  size_t off_b = 0;
  auto alloc = [&](size_t bytes) -> void* {
    void* p = ws + off_b;
    off_b += (bytes + 255) & ~(size_t)255;
    return p;
  };
  int*    flag   = (int*)alloc(sizeof(int));
  float*  maskf  = (float*)alloc((size_t)N * 4);
  int*    cnt    = (int*)alloc((size_t)N * 4);
  float*  dinv   = (float*)alloc((size_t)N * 4);
  int*    off    = (int*)alloc((size_t)N * 4);
  int*    cursor = (int*)alloc((size_t)N * 4);
  int*    bsum   = (int*)alloc(256 * 4);
  int*    gs     = (int*)alloc((size_t)G * 4);
  int*    ge     = (int*)alloc((size_t)G * 4);
  int*    csr    = (int*)alloc((size_t)E * 4);
  __half* xh     = (__half*)alloc((size_t)N * 64 * 2);
  __half* H1h    = (__half*)alloc((size_t)N * 64 * 2);
  __half* H2h    = (__half*)alloc((size_t)N * 64 * 2);
  float*  P      = (float*)alloc((size_t)N * 64 * 4);
  float*  H3     = (float*)alloc((size_t)N * 64 * 4);
  (void)ws_size;

  const int nb = (N + 255) / 256;
  const long total = (long)N * 64;
  const int prep_blocks = (int)((total + 255) / 256);

  k_detect<<<1, 1024, 0, stream>>>((const unsigned int*)mraw, N / 4, flag);
  k_prep<<<prep_blocks, 256, 0, stream>>>(x, xh, mraw, flag, maskf, cnt, gs, ge,
                                          total, N, G);
  k_cnt<<<(E + 255) / 256, 256, 0, stream>>>(src, dst, maskf, cnt, E);
  k_scan1<<<nb, 256, 0, stream>>>(cnt, maskf, dinv, off, bsum, N);
  k_scan3<<<nb, 256, 0, stream>>>(off, bsum, nb, cursor, batch, gs, ge, N);
  k_fill<<<(E + 255) / 256, 256, 0, stream>>>(src, dst, dinv, cursor, csr, E);

  const int agg_blocks = (N + 3) / 4;
  const int gemm_blocks = 2048;
  // layer 1
  k_agg<<<agg_blocks, 256, 0, stream>>>(xh, dinv, off, cnt, csr, P, N);
  k_gemm<true><<<gemm_blocks, 256, 0, stream>>>(P, W1, b1, H1h, N);
  // layer 2
  k_agg<<<agg_blocks, 256, 0, stream>>>(H1h, dinv, off, cnt, csr, P, N);
  k_gemm<true><<<gemm_blocks, 256, 0, stream>>>(P, W2, b2, H2h, N);
  // layer 3
  k_agg<<<agg_blocks, 256, 0, stream>>>(H2h, dinv, off, cnt, csr, P, N);
  k_gemm<false><<<gemm_blocks, 256, 0, stream>>>(P, W3, b3, H3, N);

  k_pool_head<<<G, 256, 0, stream>>>(H3, maskf, gs, ge, fw1, fb1, fw2, fb2, out, N, C);
}

// Round 6
// 258.828 us; speedup vs baseline: 1.0723x; 1.0723x over previous
//
#include <hip/hip_runtime.h>
#include <hip/hip_fp16.h>

// ---------------------------------------------------------------------------
// GCN pipeline v6: gather+GEMM fused per layer, dropped-node skip, 10 dispatches.
// N=50000 nodes, E=800000 edges, H=F=64, G=512 graphs, C=10 classes
// ---------------------------------------------------------------------------

// Single-block: detect whether mask is bytes (some word >1) or int32 0/1.
__global__ void k_detect(const unsigned int* __restrict__ m, int n_ints,
                         int* __restrict__ flag) {
  __shared__ int found;
  if (threadIdx.x == 0) found = 0;
  __syncthreads();
  int loc = 0;
  for (int i = threadIdx.x; i < n_ints; i += blockDim.x)
    if (m[i] > 1u) loc = 1;
  if (loc) found = 1;
  __syncthreads();
  if (threadIdx.x == 0) *flag = found;
}

// maskf + zero cnt + init gs/ge + convert x -> fp16 xh (grid covers N*64)
__global__ void k_prep(const float* __restrict__ x, __half* __restrict__ xh,
                       const void* __restrict__ mraw, const int* __restrict__ flag,
                       float* __restrict__ maskf, int* __restrict__ cnt,
                       int* __restrict__ gs, int* __restrict__ ge,
                       long total, int N, int G) {
  long idx = (long)blockIdx.x * blockDim.x + threadIdx.x;
  if (idx < total) xh[idx] = __float2half_rn(x[idx]);
  if (idx < G) { gs[idx] = 0x7fffffff; ge[idx] = -1; }
  if (idx < N) {
    float v;
    if (*flag) v = (float)((const unsigned char*)mraw)[idx];
    else       v = (float)((const int*)mraw)[idx];
    maskf[idx] = v;
    cnt[idx] = 0;
  }
}

// cnt[d] += 1 for each edge with both endpoints kept
__global__ void k_cnt(const int* __restrict__ src, const int* __restrict__ dst,
                      const float* __restrict__ maskf, int* __restrict__ cnt, int E) {
  int e = blockIdx.x * blockDim.x + threadIdx.x;
  if (e >= E) return;
  int s = src[e], d = dst[e];
  if (maskf[s] != 0.f && maskf[d] != 0.f) atomicAdd(&cnt[d], 1);
}

// block-local exclusive scan of cnt + dinv
__global__ void k_scan1(const int* __restrict__ cnt, const float* __restrict__ maskf,
                        float* __restrict__ dinv, int* __restrict__ off,
                        int* __restrict__ bsum, int N) {
  __shared__ int s[256];
  int i = blockIdx.x * 256 + threadIdx.x;
  int v = (i < N) ? cnt[i] : 0;
  if (i < N) {
    float d = (float)v + maskf[i];
    dinv[i] = (d > 0.f) ? rsqrtf(d) : 0.f;
  }
  s[threadIdx.x] = v;
  __syncthreads();
#pragma unroll
  for (int d = 1; d < 256; d <<= 1) {
    int t = (threadIdx.x >= d) ? s[threadIdx.x - d] : 0;
    __syncthreads();
    s[threadIdx.x] += t;
    __syncthreads();
  }
  if (i < N) off[i] = s[threadIdx.x] - v;
  if (threadIdx.x == 255) bsum[blockIdx.x] = s[255];
}

// finalize offsets (each block re-scans bsum in LDS; nb <= 256) + cursor +
// per-graph bounds via sorted-batch boundary detection (no atomics)
__global__ void k_scan3(int* __restrict__ off, const int* __restrict__ bsum, int nb,
                        int* __restrict__ cursor, const int* __restrict__ batch,
                        int* __restrict__ gs, int* __restrict__ ge, int N) {
  __shared__ int s[256];
  __shared__ int prefix;
  int v = (threadIdx.x < nb) ? bsum[threadIdx.x] : 0;
  s[threadIdx.x] = v;
  __syncthreads();
#pragma unroll
  for (int d = 1; d < 256; d <<= 1) {
    int t = (threadIdx.x >= d) ? s[threadIdx.x - d] : 0;
    __syncthreads();
    s[threadIdx.x] += t;
    __syncthreads();
  }
  if (threadIdx.x == blockIdx.x) prefix = s[threadIdx.x] - v;  // exclusive
  __syncthreads();
  int i = blockIdx.x * 256 + threadIdx.x;
  if (i >= N) return;
  int o = off[i] + prefix;
  off[i] = o;
  cursor[i] = o;
  int b = batch[i];
  if (i == 0 || batch[i - 1] != b) gs[b] = i;
  if (i == N - 1 || batch[i + 1] != b) ge[b] = i;
}

// Fill CSR: src index per kept edge, grouped by dst (4 B/entry).
__global__ void k_fill(const int* __restrict__ src, const int* __restrict__ dst,
                       const float* __restrict__ dinv, int* __restrict__ cursor,
                       int* __restrict__ csr, int E) {
  int e = blockIdx.x * blockDim.x + threadIdx.x;
  if (e >= E) return;
  int s = src[e], d = dst[e];
  if (dinv[s] != 0.f && dinv[d] != 0.f) {
    int p = atomicAdd(&cursor[d], 1);
    csr[p] = s;
  }
}

// Fused layer: per kept dst node (wave-per-node, grid-stride):
//   agg[0:64] = dinv[d]^2*Hh[d] + sum_e dinv[s]dinv[d]*Hh[s]   (8 edges/iter)
//   z[lane]   = relu( sum_k agg[k]*W[k][lane] + b[lane] )
// Dropped nodes (dinv==0) are skipped: their rows are never read downstream.
template <bool HALFOUT>
__global__ __launch_bounds__(256) void k_agg_gemm(const __half* __restrict__ Hh,
                                                  const float* __restrict__ dinv,
                                                  const int* __restrict__ off,
                                                  const int* __restrict__ cnt,
                                                  const int* __restrict__ csr,
                                                  const float* __restrict__ W,
                                                  const float* __restrict__ b,
                                                  void* __restrict__ out, int N) {
  const int lane = threadIdx.x & 63;
  const int wid = threadIdx.x >> 6;
  float wcol[64];
#pragma unroll
  for (int k = 0; k < 64; ++k) wcol[k] = W[k * 64 + lane];
  const float bl = b[lane];
  const int grp = lane >> 3;   // which edge of the octet
  const int q = lane & 7;      // column group: cols 8q..8q+7

  for (int d = blockIdx.x * 4 + wid; d < N; d += gridDim.x * 4) {
    const float dinv_d = dinv[d];
    if (dinv_d == 0.f) continue;  // dropped node: provably dead row
    const int base = off[d];
    const int n = cnt[d];
    float4 a0 = make_float4(0.f, 0.f, 0.f, 0.f);
    float4 a1 = make_float4(0.f, 0.f, 0.f, 0.f);
    int done = 0;
    while (done < n) {
      const int chunk = min(n - done, 64);
      int sl = (lane < chunk) ? csr[base + done + lane] : 0;
      float wl = (lane < chunk) ? dinv[sl] * dinv_d : 0.f;
      const int rounds = (chunk + 7) & ~7;
#pragma unroll 2
      for (int i = 0; i < rounds; i += 8) {
        const int j = i + grp;
        const int s = __shfl(sl, j);
        const float w = __shfl(wl, j);  // 0 for padded lanes
        const float4 raw = *(const float4*)&Hh[(long)s * 64 + q * 8];
        const __half2* hp = (const __half2*)&raw;
        const float2 f0 = __half22float2(hp[0]);
        const float2 f1 = __half22float2(hp[1]);
        const float2 f2 = __half22float2(hp[2]);
        const float2 f3 = __half22float2(hp[3]);
        a0.x = fmaf(f0.x, w, a0.x);
        a0.y = fmaf(f0.y, w, a0.y);
        a0.z = fmaf(f1.x, w, a0.z);
        a0.w = fmaf(f1.y, w, a0.w);
        a1.x = fmaf(f2.x, w, a1.x);
        a1.y = fmaf(f2.y, w, a1.y);
        a1.z = fmaf(f3.x, w, a1.z);
        a1.w = fmaf(f3.y, w, a1.w);
      }
      done += chunk;
    }
    // butterfly: every lane ends with the full cross-group sums for its q
#pragma unroll
    for (int m = 8; m <= 32; m <<= 1) {
      a0.x += __shfl_xor(a0.x, m);
      a0.y += __shfl_xor(a0.y, m);
      a0.z += __shfl_xor(a0.z, m);
      a0.w += __shfl_xor(a0.w, m);
      a1.x += __shfl_xor(a1.x, m);
      a1.y += __shfl_xor(a1.y, m);
      a1.z += __shfl_xor(a1.z, m);
      a1.w += __shfl_xor(a1.w, m);
    }
    // self-loop (all lanes, broadcast loads)
    {
      const float dii = dinv_d * dinv_d;
      const float4 raw = *(const float4*)&Hh[(long)d * 64 + q * 8];
      const __half2* hp = (const __half2*)&raw;
      const float2 f0 = __half22float2(hp[0]);
      const float2 f1 = __half22float2(hp[1]);
      const float2 f2 = __half22float2(hp[2]);
      const float2 f3 = __half22float2(hp[3]);
      a0.x = fmaf(f0.x, dii, a0.x);
      a0.y = fmaf(f0.y, dii, a0.y);
      a0.z = fmaf(f1.x, dii, a0.z);
      a0.w = fmaf(f1.y, dii, a0.w);
      a1.x = fmaf(f2.x, dii, a1.x);
      a1.y = fmaf(f2.y, dii, a1.y);
      a1.z = fmaf(f3.x, dii, a1.z);
      a1.w = fmaf(f3.y, dii, a1.w);
    }
    // GEMM epilogue: col k of agg lives in lane (k>>3), component (k&7)
    float z = bl;
#pragma unroll
    for (int k = 0; k < 64; ++k) {
      const int r = k & 7;
      float comp;
      if (r == 0) comp = a0.x; else if (r == 1) comp = a0.y;
      else if (r == 2) comp = a0.z; else if (r == 3) comp = a0.w;
      else if (r == 4) comp = a1.x; else if (r == 5) comp = a1.y;
      else if (r == 6) comp = a1.z; else comp = a1.w;
      z = fmaf(__shfl(comp, k >> 3), wcol[k], z);
    }
    z = fmaxf(z, 0.f);
    if (HALFOUT) ((__half*)out)[(long)d * 64 + lane] = __float2half_rn(z);
    else         ((float*)out)[(long)d * 64 + lane] = z;
  }
}

// Fused: per-graph max-pool over kept nodes -> MLP head -> out[grp][:]
__global__ __launch_bounds__(256) void k_pool_head(
    const float* __restrict__ H, const float* __restrict__ maskf,
    const int* __restrict__ gs, const int* __restrict__ ge,
    const float* __restrict__ fw1, const float* __restrict__ fb1,
    const float* __restrict__ fw2, const float* __restrict__ fb2,
    float* __restrict__ out, int N, int C) {
  __shared__ float sP[4][64];
  __shared__ float sg[64];
  __shared__ float sg2[64];
  const int grp = blockIdx.x;
  const int lane = threadIdx.x & 63, wid = threadIdx.x >> 6;
  const int s = gs[grp], e = ge[grp];
  float v = 0.f;
  if (s <= e) {
    for (int i = s + wid; i <= e; i += 4)
      if (maskf[i] != 0.f) v = fmaxf(v, H[(long)i * 64 + lane]);
  }
  sP[wid][lane] = v;
  __syncthreads();
  if (wid == 0)
    sg[lane] = fmaxf(fmaxf(sP[0][lane], sP[1][lane]), fmaxf(sP[2][lane], sP[3][lane]));
  __syncthreads();
  if (threadIdx.x < 64) {
    const int f = threadIdx.x;
    float acc = fb1[f];
#pragma unroll 8
    for (int k = 0; k < 64; ++k) acc = fmaf(sg[k], fw1[k * 64 + f], acc);
    sg2[f] = fmaxf(acc, 0.f);
  }
  __syncthreads();
  if (threadIdx.x < C) {
    const int c = threadIdx.x;
    float acc = fb2[c];
#pragma unroll 8
    for (int k = 0; k < 64; ++k) acc = fmaf(sg2[k], fw2[k * C + c], acc);
    out[grp * C + c] = acc;
  }
}

extern "C" void kernel_launch(void* const* d_in, const int* in_sizes, int n_in,
                              void* d_out, int out_size, void* d_ws, size_t ws_size,
                              hipStream_t stream) {
  const float* x    = (const float*)d_in[0];
  const int*   ei   = (const int*)d_in[1];
  const int*   batch= (const int*)d_in[2];
  const void*  mraw = d_in[3];
  const float* W1   = (const float*)d_in[4];
  const float* b1   = (const float*)d_in[5];
  const float* W2   = (const float*)d_in[6];
  const float* b2   = (const float*)d_in[7];
  const float* W3   = (const float*)d_in[8];
  const float* b3   = (const float*)d_in[9];
  const float* fw1  = (const float*)d_in[10];
  const float* fb1  = (const float*)d_in[11];
  const float* fw2  = (const float*)d_in[12];
  const float* fb2  = (const float*)d_in[13];
  float* out = (float*)d_out;

  const int N = in_sizes[0] / 64;
  const int E = in_sizes[1] / 2;
  const int C = in_sizes[13];
  const int* src = ei;
  const int* dst = ei + E;
  const int G = out_size / C;

  char* ws = (char*)d_ws;
  size_t off_b = 0;
  auto alloc = [&](size_t bytes) -> void* {
    void* p = ws + off_b;
    off_b += (bytes + 255) & ~(size_t)255;
    return p;
  };
  int*    flag   = (int*)alloc(sizeof(int));
  float*  maskf  = (float*)alloc((size_t)N * 4);
  int*    cnt    = (int*)alloc((size_t)N * 4);
  float*  dinv   = (float*)alloc((size_t)N * 4);
  int*    off    = (int*)alloc((size_t)N * 4);
  int*    cursor = (int*)alloc((size_t)N * 4);
  int*    bsum   = (int*)alloc(256 * 4);
  int*    gs     = (int*)alloc((size_t)G * 4);
  int*    ge     = (int*)alloc((size_t)G * 4);
  int*    csr    = (int*)alloc((size_t)E * 4);
  __half* xh     = (__half*)alloc((size_t)N * 64 * 2);
  __half* H1h    = (__half*)alloc((size_t)N * 64 * 2);
  __half* H2h    = (__half*)alloc((size_t)N * 64 * 2);
  float*  H3     = (float*)alloc((size_t)N * 64 * 4);
  (void)ws_size;

  const int nb = (N + 255) / 256;
  const long total = (long)N * 64;
  const int prep_blocks = (int)((total + 255) / 256);

  k_detect<<<1, 1024, 0, stream>>>((const unsigned int*)mraw, N / 4, flag);
  k_prep<<<prep_blocks, 256, 0, stream>>>(x, xh, mraw, flag, maskf, cnt, gs, ge,
                                          total, N, G);
  k_cnt<<<(E + 255) / 256, 256, 0, stream>>>(src, dst, maskf, cnt, E);
  k_scan1<<<nb, 256, 0, stream>>>(cnt, maskf, dinv, off, bsum, N);
  k_scan3<<<nb, 256, 0, stream>>>(off, bsum, nb, cursor, batch, gs, ge, N);
  k_fill<<<(E + 255) / 256, 256, 0, stream>>>(src, dst, dinv, cursor, csr, E);

  const int lay_blocks = 2048;
  k_agg_gemm<true ><<<lay_blocks, 256, 0, stream>>>(xh,  dinv, off, cnt, csr, W1, b1, H1h, N);
  k_agg_gemm<true ><<<lay_blocks, 256, 0, stream>>>(H1h, dinv, off, cnt, csr, W2, b2, H2h, N);
  k_agg_gemm<false><<<lay_blocks, 256, 0, stream>>>(H2h, dinv, off, cnt, csr, W3, b3, H3,  N);

  k_pool_head<<<G, 256, 0, stream>>>(H3, maskf, gs, ge, fw1, fb1, fw2, fb2, out, N, C);
}

// Round 7
// 252.542 us; speedup vs baseline: 1.0990x; 1.0249x over previous
//
#include <hip/hip_runtime.h>
#include <hip/hip_fp16.h>

// ---------------------------------------------------------------------------
// GCN pipeline v7: fused layer w/ 128-VGPR budget, int2 CSR (w precomputed,
// self-loops in CSR), packed (off,cnt). 10 dispatches.
// N=50000 nodes, E=800000 edges, H=F=64, G=512 graphs, C=10 classes
// ---------------------------------------------------------------------------

// Single-block: detect whether mask is bytes (some word >1) or int32 0/1.
__global__ void k_detect(const unsigned int* __restrict__ m, int n_ints,
                         int* __restrict__ flag) {
  __shared__ int found;
  if (threadIdx.x == 0) found = 0;
  __syncthreads();
  int loc = 0;
  for (int i = threadIdx.x; i < n_ints; i += blockDim.x)
    if (m[i] > 1u) loc = 1;
  if (loc) found = 1;
  __syncthreads();
  if (threadIdx.x == 0) *flag = found;
}

// maskf + zero cnt + init gs/ge + convert x -> fp16 xh (grid covers N*64)
__global__ void k_prep(const float* __restrict__ x, __half* __restrict__ xh,
                       const void* __restrict__ mraw, const int* __restrict__ flag,
                       float* __restrict__ maskf, int* __restrict__ cnt,
                       int* __restrict__ gs, int* __restrict__ ge,
                       long total, int N, int G) {
  long idx = (long)blockIdx.x * blockDim.x + threadIdx.x;
  if (idx < total) xh[idx] = __float2half_rn(x[idx]);
  if (idx < G) { gs[idx] = 0x7fffffff; ge[idx] = -1; }
  if (idx < N) {
    float v;
    if (*flag) v = (float)((const unsigned char*)mraw)[idx];
    else       v = (float)((const int*)mraw)[idx];
    maskf[idx] = v;
    cnt[idx] = 0;
  }
}

// cnt[d] += 1 for each edge with both endpoints kept
__global__ void k_cnt(const int* __restrict__ src, const int* __restrict__ dst,
                      const float* __restrict__ maskf, int* __restrict__ cnt, int E) {
  int e = blockIdx.x * blockDim.x + threadIdx.x;
  if (e >= E) return;
  int s = src[e], d = dst[e];
  if (maskf[s] != 0.f && maskf[d] != 0.f) atomicAdd(&cnt[d], 1);
}

// dinv + slots(=cnt+kept) scan; slots stashed in cursor[] for scan3
__global__ void k_scan1(const int* __restrict__ cnt, const float* __restrict__ maskf,
                        float* __restrict__ dinv, int* __restrict__ off,
                        int* __restrict__ cursor, int* __restrict__ bsum, int N) {
  __shared__ int s[256];
  int i = blockIdx.x * 256 + threadIdx.x;
  int c = (i < N) ? cnt[i] : 0;
  float mk = (i < N) ? maskf[i] : 0.f;
  float dsum = (float)c + mk;
  if (i < N) dinv[i] = (dsum > 0.f) ? rsqrtf(dsum) : 0.f;
  int v = c + (mk != 0.f ? 1 : 0);  // slots incl. self-loop
  if (i < N) cursor[i] = v;         // stash slots
  s[threadIdx.x] = v;
  __syncthreads();
#pragma unroll
  for (int d = 1; d < 256; d <<= 1) {
    int t = (threadIdx.x >= d) ? s[threadIdx.x - d] : 0;
    __syncthreads();
    s[threadIdx.x] += t;
    __syncthreads();
  }
  if (i < N) off[i] = s[threadIdx.x] - v;
  if (threadIdx.x == 255) bsum[blockIdx.x] = s[255];
}

// finalize offsets; offcnt=(off,slots); write self-loop CSR entry; cursor=off+1
// for kept nodes; per-graph bounds via sorted-batch boundary detection.
__global__ void k_scan3(const int* __restrict__ off_loc, const int* __restrict__ bsum,
                        int nb, int* __restrict__ cursor, int2* __restrict__ offcnt,
                        int2* __restrict__ csr, const float* __restrict__ dinv,
                        const int* __restrict__ batch,
                        int* __restrict__ gs, int* __restrict__ ge, int N) {
  __shared__ int s[256];
  __shared__ int prefix;
  int v = (threadIdx.x < nb) ? bsum[threadIdx.x] : 0;
  s[threadIdx.x] = v;
  __syncthreads();
#pragma unroll
  for (int d = 1; d < 256; d <<= 1) {
    int t = (threadIdx.x >= d) ? s[threadIdx.x - d] : 0;
    __syncthreads();
    s[threadIdx.x] += t;
    __syncthreads();
  }
  if (threadIdx.x == blockIdx.x) prefix = s[threadIdx.x] - v;  // exclusive
  __syncthreads();
  int i = blockIdx.x * 256 + threadIdx.x;
  if (i >= N) return;
  int o = off_loc[i] + prefix;
  int slots = cursor[i];  // stashed by scan1
  offcnt[i] = make_int2(o, slots);
  float di = dinv[i];
  if (di != 0.f) {
    csr[o] = make_int2(i, __float_as_int(di * di));  // self-loop entry
    cursor[i] = o + 1;
  } else {
    cursor[i] = o;
  }
  int b = batch[i];
  if (i == 0 || batch[i - 1] != b) gs[b] = i;
  if (i == N - 1 || batch[i + 1] != b) ge[b] = i;
}

// Fill CSR: (src, weight) per kept edge, grouped by dst.
__global__ void k_fill(const int* __restrict__ src, const int* __restrict__ dst,
                       const float* __restrict__ dinv, int* __restrict__ cursor,
                       int2* __restrict__ csr, int E) {
  int e = blockIdx.x * blockDim.x + threadIdx.x;
  if (e >= E) return;
  int s = src[e], d = dst[e];
  float ws = dinv[s], wd = dinv[d];
  if (ws != 0.f && wd != 0.f) {
    int p = atomicAdd(&cursor[d], 1);
    csr[p] = make_int2(s, __float_as_int(ws * wd));
  }
}

// Fused layer, wave per kept dst node (grid-stride):
//   agg[0:64] = sum_{e in csr[d]} w_e * Hh[src_e][:]   (self-loop is an entry)
//   z[lane]   = relu( sum_k agg[k]*W[k][lane] + b[lane] )
// 4 blocks/CU (<=128 VGPR) so wcol[64] stays in registers.
template <bool HALFOUT>
__global__ __launch_bounds__(256, 4) void k_agg_gemm(const __half* __restrict__ Hh,
                                                     const int2* __restrict__ offcnt,
                                                     const int2* __restrict__ csr,
                                                     const float* __restrict__ W,
                                                     const float* __restrict__ b,
                                                     void* __restrict__ out, int N) {
  const int lane = threadIdx.x & 63;
  const int wid = threadIdx.x >> 6;
  float wcol[64];
#pragma unroll
  for (int k = 0; k < 64; ++k) wcol[k] = W[k * 64 + lane];
  const float bl = b[lane];
  const int grp = lane >> 3;   // which edge of the octet
  const int q = lane & 7;      // column group: cols 8q..8q+7
  const __half* __restrict__ Hq = Hh + q * 8;

  for (int d = blockIdx.x * 4 + wid; d < N; d += gridDim.x * 4) {
    const int2 oc = offcnt[d];
    const int n = oc.y;
    if (n == 0) continue;  // dropped node: row provably dead downstream
    float4 a0 = make_float4(0.f, 0.f, 0.f, 0.f);
    float4 a1 = make_float4(0.f, 0.f, 0.f, 0.f);
    int done = 0;
    while (done < n) {
      const int chunk = min(n - done, 64);
      int2 ce = (lane < chunk) ? csr[oc.x + done + lane] : make_int2(0, 0);
      const int rounds = (chunk + 7) & ~7;
#pragma unroll 2
      for (int i = 0; i < rounds; i += 8) {
        const int j = i + grp;
        const int s = __shfl(ce.x, j);
        const float w = __int_as_float(__shfl(ce.y, j));  // 0 for padded lanes
        const float4 raw = *(const float4*)&Hq[(long)s * 64];
        const __half2* hp = (const __half2*)&raw;
        const float2 f0 = __half22float2(hp[0]);
        const float2 f1 = __half22float2(hp[1]);
        const float2 f2 = __half22float2(hp[2]);
        const float2 f3 = __half22float2(hp[3]);
        a0.x = fmaf(f0.x, w, a0.x);
        a0.y = fmaf(f0.y, w, a0.y);
        a0.z = fmaf(f1.x, w, a0.z);
        a0.w = fmaf(f1.y, w, a0.w);
        a1.x = fmaf(f2.x, w, a1.x);
        a1.y = fmaf(f2.y, w, a1.y);
        a1.z = fmaf(f3.x, w, a1.z);
        a1.w = fmaf(f3.y, w, a1.w);
      }
      done += chunk;
    }
    // butterfly: every lane ends with full cross-group sums for its q
#pragma unroll
    for (int m = 8; m <= 32; m <<= 1) {
      a0.x += __shfl_xor(a0.x, m);
      a0.y += __shfl_xor(a0.y, m);
      a0.z += __shfl_xor(a0.z, m);
      a0.w += __shfl_xor(a0.w, m);
      a1.x += __shfl_xor(a1.x, m);
      a1.y += __shfl_xor(a1.y, m);
      a1.z += __shfl_xor(a1.z, m);
      a1.w += __shfl_xor(a1.w, m);
    }
    // GEMM epilogue: col k of agg lives in lane (k>>3), component (k&7).
    // Two interleaved fma chains.
    float z0 = bl, z1 = 0.f;
#pragma unroll
    for (int k = 0; k < 64; k += 2) {
      const int r0 = k & 7;
      float c0;
      if (r0 == 0) c0 = a0.x; else if (r0 == 1) c0 = a0.y;
      else if (r0 == 2) c0 = a0.z; else if (r0 == 3) c0 = a0.w;
      else if (r0 == 4) c0 = a1.x; else if (r0 == 5) c0 = a1.y;
      else if (r0 == 6) c0 = a1.z; else c0 = a1.w;
      const int r1 = (k + 1) & 7;
      float c1;
      if (r1 == 0) c1 = a0.x; else if (r1 == 1) c1 = a0.y;
      else if (r1 == 2) c1 = a0.z; else if (r1 == 3) c1 = a0.w;
      else if (r1 == 4) c1 = a1.x; else if (r1 == 5) c1 = a1.y;
      else if (r1 == 6) c1 = a1.z; else c1 = a1.w;
      z0 = fmaf(__shfl(c0, k >> 3), wcol[k], z0);
      z1 = fmaf(__shfl(c1, (k + 1) >> 3), wcol[k + 1], z1);
    }
    const float z = fmaxf(z0 + z1, 0.f);
    if (HALFOUT) ((__half*)out)[(long)d * 64 + lane] = __float2half_rn(z);
    else         ((float*)out)[(long)d * 64 + lane] = z;
  }
}

// Fused: per-graph max-pool over kept nodes -> MLP head -> out[grp][:]
__global__ __launch_bounds__(256) void k_pool_head(
    const float* __restrict__ H, const float* __restrict__ maskf,
    const int* __restrict__ gs, const int* __restrict__ ge,
    const float* __restrict__ fw1, const float* __restrict__ fb1,
    const float* __restrict__ fw2, const float* __restrict__ fb2,
    float* __restrict__ out, int N, int C) {
  __shared__ float sP[4][64];
  __shared__ float sg[64];
  __shared__ float sg2[64];
  const int grp = blockIdx.x;
  const int lane = threadIdx.x & 63, wid = threadIdx.x >> 6;
  const int s = gs[grp], e = ge[grp];
  float v = 0.f;
  if (s <= e) {
    for (int i = s + wid; i <= e; i += 4)
      if (maskf[i] != 0.f) v = fmaxf(v, H[(long)i * 64 + lane]);
  }
  sP[wid][lane] = v;
  __syncthreads();
  if (wid == 0)
    sg[lane] = fmaxf(fmaxf(sP[0][lane], sP[1][lane]), fmaxf(sP[2][lane], sP[3][lane]));
  __syncthreads();
  if (threadIdx.x < 64) {
    const int f = threadIdx.x;
    float acc = fb1[f];
#pragma unroll 8
    for (int k = 0; k < 64; ++k) acc = fmaf(sg[k], fw1[k * 64 + f], acc);
    sg2[f] = fmaxf(acc, 0.f);
  }
  __syncthreads();
  if (threadIdx.x < C) {
    const int c = threadIdx.x;
    float acc = fb2[c];
#pragma unroll 8
    for (int k = 0; k < 64; ++k) acc = fmaf(sg2[k], fw2[k * C + c], acc);
    out[grp * C + c] = acc;
  }
}

extern "C" void kernel_launch(void* const* d_in, const int* in_sizes, int n_in,
                              void* d_out, int out_size, void* d_ws, size_t ws_size,
                              hipStream_t stream) {
  const float* x    = (const float*)d_in[0];
  const int*   ei   = (const int*)d_in[1];
  const int*   batch= (const int*)d_in[2];
  const void*  mraw = d_in[3];
  const float* W1   = (const float*)d_in[4];
  const float* b1   = (const float*)d_in[5];
  const float* W2   = (const float*)d_in[6];
  const float* b2   = (const float*)d_in[7];
  const float* W3   = (const float*)d_in[8];
  const float* b3   = (const float*)d_in[9];
  const float* fw1  = (const float*)d_in[10];
  const float* fb1  = (const float*)d_in[11];
  const float* fw2  = (const float*)d_in[12];
  const float* fb2  = (const float*)d_in[13];
  float* out = (float*)d_out;

  const int N = in_sizes[0] / 64;
  const int E = in_sizes[1] / 2;
  const int C = in_sizes[13];
  const int* src = ei;
  const int* dst = ei + E;
  const int G = out_size / C;

  char* ws = (char*)d_ws;
  size_t off_b = 0;
  auto alloc = [&](size_t bytes) -> void* {
    void* p = ws + off_b;
    off_b += (bytes + 255) & ~(size_t)255;
    return p;
  };
  int*    flag   = (int*)alloc(sizeof(int));
  float*  maskf  = (float*)alloc((size_t)N * 4);
  int*    cnt    = (int*)alloc((size_t)N * 4);
  float*  dinv   = (float*)alloc((size_t)N * 4);
  int*    off    = (int*)alloc((size_t)N * 4);
  int*    cursor = (int*)alloc((size_t)N * 4);
  int*    bsum   = (int*)alloc(256 * 4);
  int*    gs     = (int*)alloc((size_t)G * 4);
  int*    ge     = (int*)alloc((size_t)G * 4);
  int2*   offcnt = (int2*)alloc((size_t)N * 8);
  int2*   csr    = (int2*)alloc(((size_t)E + N) * 8);
  __half* xh     = (__half*)alloc((size_t)N * 64 * 2);
  __half* H1h    = (__half*)alloc((size_t)N * 64 * 2);
  __half* H2h    = (__half*)alloc((size_t)N * 64 * 2);
  float*  H3     = (float*)alloc((size_t)N * 64 * 4);
  (void)ws_size;

  const int nb = (N + 255) / 256;
  const long total = (long)N * 64;
  const int prep_blocks = (int)((total + 255) / 256);

  k_detect<<<1, 1024, 0, stream>>>((const unsigned int*)mraw, N / 4, flag);
  k_prep<<<prep_blocks, 256, 0, stream>>>(x, xh, mraw, flag, maskf, cnt, gs, ge,
                                          total, N, G);
  k_cnt<<<(E + 255) / 256, 256, 0, stream>>>(src, dst, maskf, cnt, E);
  k_scan1<<<nb, 256, 0, stream>>>(cnt, maskf, dinv, off, cursor, bsum, N);
  k_scan3<<<nb, 256, 0, stream>>>(off, bsum, nb, cursor, offcnt, csr, dinv,
                                  batch, gs, ge, N);
  k_fill<<<(E + 255) / 256, 256, 0, stream>>>(src, dst, dinv, cursor, csr, E);

  const int lay_blocks = 1024;  // 4 blocks/CU exactly
  k_agg_gemm<true ><<<lay_blocks, 256, 0, stream>>>(xh,  offcnt, csr, W1, b1, H1h, N);
  k_agg_gemm<true ><<<lay_blocks, 256, 0, stream>>>(H1h, offcnt, csr, W2, b2, H2h, N);
  k_agg_gemm<false><<<lay_blocks, 256, 0, stream>>>(H2h, offcnt, csr, W3, b3, H3,  N);

  k_pool_head<<<G, 256, 0, stream>>>(H3, maskf, gs, ge, fw1, fb1, fw2, fb2, out, N, C);
}